// Round 7
// baseline (5594.267 us; speedup 1.0000x reference)
//
#include <hip/hip_runtime.h>
#include <cmath>

// DGCNN: B=8, N=2048, k=20, dims 3->64->128->256, fp32 throughout.
static constexpr int Bb  = 8;
static constexpr int Nn  = 2048;
static constexpr int KNB = 20;
static constexpr int NPT = Bb * Nn;
#define EPSBN 1e-5f

// LDS column swizzle: maps 4-float groups so 16-address b128 reads cover all
// 32 banks 2x (2-way = free) instead of 4 bank-groups 4x.
__device__ __forceinline__ int permc(int c) { return c ^ (4 * (c >> 5)); }

// ---------------------------------------------------------------- row |x|^2
__global__ __launch_bounds__(256) void row_sumsq_k(const float* __restrict__ f,
                                                   float* __restrict__ xx, int C) {
  int g = blockIdx.x * 256 + threadIdx.x;
  if (g >= NPT) return;
  const float* r = f + (size_t)g * C;
  float s = 0.f;
  for (int j = 0; j < C; ++j) { float v = r[j]; s += v * v; }
  xx[g] = s;
}

// ------------------------------------------------- neg_dist, symmetric 128x128
// nd[n][m] = 2*x_n.x_m - |x_n|^2 - |x_m|^2 ; diag forced to exactly 0.
// Upper-triangular block pairs (136/batch); mirror via 32-row LDS transpose
// chunks (buffer unioned with dead As/Bs -> 16.9 KB). NO launch_bounds
// min-waves: acc[8][8] sets a ~112 VGPR floor; forcing 4 waves/SIMD (R6)
// spilled to scratch (FETCH 37->412 MB, 2x slowdown). Plain (256) gives
// ~112 VGPR -> 4 waves/SIMD naturally, LDS allows 9 blocks.
__global__ __launch_bounds__(256) void dist_k(const float* __restrict__ f,
                                              const float* __restrict__ xx,
                                              float* __restrict__ nd, int C) {
  __shared__ float lds[32 * 132];                       // 16.9 KB, unioned
  float (*As)[132] = (float(*)[132])lds;                // rows 0..15
  float (*Bs)[132] = (float(*)[132])(lds + 16 * 132);   // rows 16..31
  float* Sc = lds;                                      // transpose buf (32x132)
  int tid = threadIdx.x, tx = tid & 15, ty = tid >> 4;
  int b = blockIdx.z;
  const float* fb  = f  + (size_t)b * Nn * C;
  const float* xxb = xx + (size_t)b * Nn;
  float* ndb = nd + (size_t)b * Nn * Nn;
  // triangular decode: blockIdx.x in [0,136) -> (rblk, cblk), rblk <= cblk
  int p = blockIdx.x, rblk = 0;
  while (p >= 16 - rblk) { p -= 16 - rblk; ++rblk; }
  int rb = rblk * 128, cb = (rblk + p) * 128;
  bool diag = (rb == cb);
  int kk0 = tid & 15, rr = tid >> 4;
  float acc[8][8] = {};
  for (int k0 = 0; k0 < C; k0 += 16) {
    int k = k0 + kk0;
    bool ok = k < C;
    #pragma unroll
    for (int t = 0; t < 8; ++t) {
      int r2 = rr + 16 * t;
      int c2 = permc(r2);
      As[kk0][c2] = ok ? fb[(size_t)(rb + r2) * C + k] : 0.f;
      Bs[kk0][c2] = ok ? fb[(size_t)(cb + r2) * C + k] : 0.f;
    }
    __syncthreads();
    #pragma unroll
    for (int kk = 0; kk < 16; ++kk) {
      float4 a0 = *(const float4*)&As[kk][permc(8 * ty)];
      float4 a1 = *(const float4*)&As[kk][permc(8 * ty + 4)];
      float4 b0 = *(const float4*)&Bs[kk][permc(8 * tx)];
      float4 b1 = *(const float4*)&Bs[kk][permc(8 * tx + 4)];
      float av[8] = {a0.x, a0.y, a0.z, a0.w, a1.x, a1.y, a1.z, a1.w};
      float bv[8] = {b0.x, b0.y, b0.z, b0.w, b1.x, b1.y, b1.z, b1.w};
      #pragma unroll
      for (int i = 0; i < 8; ++i)
        #pragma unroll
        for (int j = 0; j < 8; ++j) acc[i][j] += av[i] * bv[j];
    }
    __syncthreads();
  }
  // epilogue: finalize into acc, store tile (+ mirrored tile if off-diag)
  float xr[8], xc[8];
  #pragma unroll
  for (int i = 0; i < 8; ++i) xr[i] = xxb[rb + 8 * ty + i];
  #pragma unroll
  for (int j = 0; j < 8; ++j) xc[j] = xxb[cb + 8 * tx + j];
  #pragma unroll
  for (int i = 0; i < 8; ++i) {
    int grow = rb + 8 * ty + i;
    #pragma unroll
    for (int j = 0; j < 8; ++j) {
      int gcol = cb + 8 * tx + j;
      float v = 2.f * acc[i][j] - xr[i] - xc[j];
      acc[i][j] = (grow == gcol) ? 0.f : v;
    }
    *(float4*)&ndb[(size_t)grow * Nn + cb + 8 * tx] =
        make_float4(acc[i][0], acc[i][1], acc[i][2], acc[i][3]);
    *(float4*)&ndb[(size_t)grow * Nn + cb + 8 * tx + 4] =
        make_float4(acc[i][4], acc[i][5], acc[i][6], acc[i][7]);
  }
  if (!diag) {
    int lr = tid >> 3, q8 = tid & 7;
    #pragma unroll
    for (int h = 0; h < 4; ++h) {
      __syncthreads();
      if ((tx >> 2) == h) {
        int txl = tx & 3;
        #pragma unroll
        for (int j = 0; j < 8; ++j) {
          // rotate the float4 half by (txl+u)&1 so txl enters the bank index
          // (132*8 = 0 mod 32 banks -> without rotation all txl collide 4-way)
          #pragma unroll
          for (int u = 0; u < 2; ++u) {
            int ib = 4 * ((txl + u) & 1);
            *(float4*)&Sc[(8 * txl + j) * 132 + 8 * ty + ib] =
                make_float4(acc[ib][j], acc[ib + 1][j], acc[ib + 2][j], acc[ib + 3][j]);
          }
        }
      }
      __syncthreads();
      int grow = cb + 32 * h + lr;
      #pragma unroll
      for (int u = 0; u < 4; ++u) {
        float4 v = *(const float4*)&Sc[lr * 132 + 4 * (q8 + 8 * u)];
        *(float4*)&ndb[(size_t)grow * Nn + rb + 4 * (q8 + 8 * u)] = v;
      }
    }
  }
}

// ------------------------------------------------- wave0 suffix-scan digit find
__device__ __forceinline__ void find_digit64(const int* hist, int tid,
                                             int* s_digit, int* s_kneed) {
  if (tid < 64) {
    int kneed = *s_kneed;
    int l = tid;
    int h0 = hist[4 * l], h1 = hist[4 * l + 1], h2 = hist[4 * l + 2], h3 = hist[4 * l + 3];
    int s3 = h3, s2 = h2 + s3, s1 = h1 + s2, s0 = h0 + s1;
    int cum = s0;
    #pragma unroll
    for (int off = 1; off < 64; off <<= 1) {
      int v = __shfl_down(cum, off, 64);
      if (l + off < 64) cum += v;
    }
    int ab = cum - s0;
    int suf0 = ab + s0, suf1 = ab + s1, suf2 = ab + s2, suf3 = ab + s3, suf4 = ab;
    if (suf0 >= kneed && suf1 < kneed) { *s_digit = 4 * l;     *s_kneed = kneed - suf1; }
    if (suf1 >= kneed && suf2 < kneed) { *s_digit = 4 * l + 1; *s_kneed = kneed - suf2; }
    if (suf2 >= kneed && suf3 < kneed) { *s_digit = 4 * l + 2; *s_kneed = kneed - suf3; }
    if (suf3 >= kneed && suf4 < kneed) { *s_digit = 4 * l + 3; *s_kneed = kneed - suf4; }
  }
}

// ------------------------------------------------- top-20: radix select per row
__global__ __launch_bounds__(256) void topk_k(const float* __restrict__ nd,
                                              int* __restrict__ outidx) {
  __shared__ unsigned keys[Nn];
  __shared__ unsigned ck[Nn];
  __shared__ short cidx[Nn];
  __shared__ int hist[256];
  __shared__ int s_digit, s_kneed, s_cnt, s_ncand;
  int tid = threadIdx.x;
  const float* row = nd + (size_t)blockIdx.x * Nn;
  int* orow = outidx + (size_t)blockIdx.x * KNB;
  if (tid == 0) { s_kneed = KNB; s_cnt = 0; s_ncand = 0; }
  hist[tid] = 0;
  __syncthreads();
  #pragma unroll
  for (int t = 0; t < Nn / 256; ++t) {
    int i = tid + 256 * t;
    unsigned u = __float_as_uint(row[i]);
    unsigned k = (u & 0x80000000u) ? ~u : (u | 0x80000000u);
    keys[i] = k;
    atomicAdd(&hist[k >> 24], 1);
  }
  __syncthreads();
  find_digit64(hist, tid, &s_digit, &s_kneed);
  __syncthreads();
  unsigned dig1 = (unsigned)s_digit;
  unsigned prefix = dig1 << 24;
  #pragma unroll
  for (int t = 0; t < Nn / 256; ++t) {
    int i = tid + 256 * t;
    unsigned k = keys[i];
    unsigned bb = k >> 24;
    if (bb > dig1) { int p = atomicAdd(&s_cnt, 1); orow[p] = i; }
    else if (bb == dig1) { int p = atomicAdd(&s_ncand, 1); ck[p] = k; cidx[p] = (short)i; }
  }
  __syncthreads();
  int nc = s_ncand;
  for (int shift = 16; shift >= 0; shift -= 8) {
    unsigned pm = 0xFFFFFFFFu << (shift + 8);
    hist[tid] = 0;
    __syncthreads();
    for (int j = tid; j < nc; j += 256) {
      unsigned k = ck[j];
      if (((k ^ prefix) & pm) == 0) atomicAdd(&hist[(k >> shift) & 255], 1);
    }
    __syncthreads();
    find_digit64(hist, tid, &s_digit, &s_kneed);
    __syncthreads();
    prefix |= ((unsigned)s_digit) << shift;
  }
  unsigned T = prefix;
  for (int j = tid; j < nc; j += 256)
    if (ck[j] > T) { int p = atomicAdd(&s_cnt, 1); orow[p] = (int)cidx[j]; }
  int kF = s_kneed, base = KNB - kF, last = -1;
  for (int r = 0; r < kF; ++r) {
    int loc = 0x7fffffff;
    for (int j = tid; j < nc; j += 256)
      if (ck[j] == T && (int)cidx[j] > last) loc = min(loc, (int)cidx[j]);
    hist[tid] = loc;
    __syncthreads();
    for (int s = 128; s > 0; s >>= 1) {
      if (tid < s) hist[tid] = min(hist[tid], hist[tid + s]);
      __syncthreads();
    }
    last = hist[0];
    if (tid == 0) orow[base + r] = last;
    __syncthreads();
  }
}

// ------------------------------------------------- fused GEMM: A = X*W1^T + b, Bv = X*W2^T
__global__ __launch_bounds__(256) void gemmAB_k(const float* __restrict__ X,
                                                const float* __restrict__ W,
                                                const float* __restrict__ bias,
                                                float* __restrict__ A,
                                                float* __restrict__ Bv,
                                                int COUT, int CIN) {
  __shared__ float Xs[16][132];
  __shared__ float Ws[16][132];
  int tid = threadIdx.x, tx = tid & 15, ty = tid >> 4;
  int mb = blockIdx.y * 128, cb = blockIdx.x * 128;
  int kk0 = tid & 15, rr = tid >> 4;
  int ldw = 2 * CIN;
  float acc[8][8] = {};
  for (int k0 = 0; k0 < CIN; k0 += 16) {
    int k = k0 + kk0;
    bool ok = k < CIN;
    #pragma unroll
    for (int r2 = rr; r2 < 128; r2 += 16) {
      Xs[kk0][permc(r2)] = ok ? X[(size_t)(mb + r2) * CIN + k] : 0.f;
      int c2 = cb + r2;
      const float* wr = (c2 < COUT) ? (W + (size_t)c2 * ldw)
                                    : (W + (size_t)(c2 - COUT) * ldw + CIN);
      Ws[kk0][permc(r2)] = ok ? wr[k] : 0.f;
    }
    __syncthreads();
    #pragma unroll
    for (int kk = 0; kk < 16; ++kk) {
      float4 a0 = *(const float4*)&Xs[kk][permc(8 * ty)];
      float4 a1 = *(const float4*)&Xs[kk][permc(8 * ty + 4)];
      float4 b0 = *(const float4*)&Ws[kk][permc(8 * tx)];
      float4 b1 = *(const float4*)&Ws[kk][permc(8 * tx + 4)];
      float av[8] = {a0.x, a0.y, a0.z, a0.w, a1.x, a1.y, a1.z, a1.w};
      float bv[8] = {b0.x, b0.y, b0.z, b0.w, b1.x, b1.y, b1.z, b1.w};
      #pragma unroll
      for (int i = 0; i < 8; ++i)
        #pragma unroll
        for (int j = 0; j < 8; ++j) acc[i][j] += av[i] * bv[j];
    }
    __syncthreads();
  }
  int c0 = cb + 8 * tx;
  bool isA = (c0 < COUT);
  float bb[8] = {0, 0, 0, 0, 0, 0, 0, 0};
  if (isA) {
    float4 b4a = *(const float4*)&bias[c0];
    float4 b4b = *(const float4*)&bias[c0 + 4];
    bb[0] = b4a.x; bb[1] = b4a.y; bb[2] = b4a.z; bb[3] = b4a.w;
    bb[4] = b4b.x; bb[5] = b4b.y; bb[6] = b4b.z; bb[7] = b4b.w;
  }
  float* dst = isA ? A : Bv;
  int cc = isA ? c0 : (c0 - COUT);
  #pragma unroll
  for (int i = 0; i < 8; ++i) {
    int m = mb + 8 * ty + i;
    *(float4*)&dst[(size_t)m * COUT + cc] =
        make_float4(acc[i][0] + bb[0], acc[i][1] + bb[1], acc[i][2] + bb[2], acc[i][3] + bb[3]);
    *(float4*)&dst[(size_t)m * COUT + cc + 4] =
        make_float4(acc[i][4] + bb[4], acc[i][5] + bb[5], acc[i][6] + bb[6], acc[i][7] + bb[7]);
  }
}

// ------------------------------------------------- gather-combine + stats
// XCD-aware: batch = blockIdx.x % 8 so each XCD's L2 caches one batch's Bv slice.
template <int COUT>
__global__ __launch_bounds__(256) void combine_k(const float* __restrict__ A,
                                                 const float* __restrict__ Bv,
                                                 const int* __restrict__ idx,
                                                 float* __restrict__ maxh,
                                                 float* __restrict__ minh,
                                                 float* __restrict__ gsum,
                                                 float* __restrict__ gsumsq) {
  constexpr int TPP = COUT / 4;
  constexpr int P = 256 / TPP;
  constexpr int PTS = 16;
  __shared__ float red[8][256];
  int tid = threadIdx.x;
  int p = tid / TPP, cq = tid % TPP;
  int b = blockIdx.x & 7, chunk = blockIdx.x >> 3;
  int nbase = b * Nn + chunk * PTS;
  const float4* A4 = (const float4*)A;
  const float4* B4 = (const float4*)Bv;
  float4 ts = make_float4(0, 0, 0, 0), ts2 = make_float4(0, 0, 0, 0);
  for (int it = 0; it < PTS / P; ++it) {
    int n = nbase + it * P + p;
    float4 a  = A4[(size_t)n * TPP + cq];
    float4 bc = B4[(size_t)n * TPP + cq];
    float4 base = make_float4(a.x - bc.x, a.y - bc.y, a.z - bc.z, a.w - bc.w);
    float4 mx = make_float4(-INFINITY, -INFINITY, -INFINITY, -INFINITY);
    float4 mn = make_float4(INFINITY, INFINITY, INFINITY, INFINITY);
    int gb = b * Nn;
    const int* ip = idx + (size_t)n * KNB;
    for (int k = 0; k < KNB; ++k) {
      int m = ip[k];
      float4 bn = B4[(size_t)(gb + m) * TPP + cq];
      float4 h = make_float4(base.x + bn.x, base.y + bn.y, base.z + bn.z, base.w + bn.w);
      mx.x = fmaxf(mx.x, h.x); mx.y = fmaxf(mx.y, h.y);
      mx.z = fmaxf(mx.z, h.z); mx.w = fmaxf(mx.w, h.w);
      mn.x = fminf(mn.x, h.x); mn.y = fminf(mn.y, h.y);
      mn.z = fminf(mn.z, h.z); mn.w = fminf(mn.w, h.w);
      ts.x += h.x; ts.y += h.y; ts.z += h.z; ts.w += h.w;
      ts2.x += h.x * h.x; ts2.y += h.y * h.y; ts2.z += h.z * h.z; ts2.w += h.w * h.w;
    }
    ((float4*)maxh)[(size_t)n * TPP + cq] = mx;
    ((float4*)minh)[(size_t)n * TPP + cq] = mn;
  }
  red[0][tid] = ts.x;  red[1][tid] = ts.y;  red[2][tid] = ts.z;  red[3][tid] = ts.w;
  red[4][tid] = ts2.x; red[5][tid] = ts2.y; red[6][tid] = ts2.z; red[7][tid] = ts2.w;
  __syncthreads();
  if (tid < COUT) {
    int q = tid & 3, g = tid >> 2;
    float s = 0.f, s2 = 0.f;
    for (int pp = 0; pp < P; ++pp) {
      int t2 = pp * TPP + g;
      s += red[q][t2]; s2 += red[4 + q][t2];
    }
    atomicAdd(&gsum[tid], s);
    atomicAdd(&gsumsq[tid], s2);
  }
}

// ------------------------------------------------- BN scale/shift per channel
__global__ void stats_k(const float* __restrict__ gsum, const float* __restrict__ gsumsq,
                        const float* __restrict__ gamma, const float* __restrict__ beta,
                        float* __restrict__ sA, float* __restrict__ sB, int COUT) {
  int c = threadIdx.x;
  if (c < COUT) {
    const float cnt = (float)((size_t)Bb * Nn * KNB);
    float mean = gsum[c] / cnt;
    float var = gsumsq[c] / cnt - mean * mean;
    var = fmaxf(var, 0.f);
    float s = gamma[c] * rsqrtf(var + EPSBN);
    sA[c] = s;
    sB[c] = beta[c] - mean * s;
  }
}

// ------------------------------------------------- apply BN+ReLU
__global__ __launch_bounds__(256) void apply_k(const float* __restrict__ maxh,
                                               const float* __restrict__ minh,
                                               const float* __restrict__ sA,
                                               const float* __restrict__ sB,
                                               float* __restrict__ out, int COUT) {
  int i = blockIdx.x * 256 + threadIdx.x;
  if (i >= NPT * COUT) return;
  int c = i % COUT;
  float s = sA[c];
  float h = (s >= 0.f) ? maxh[i] : minh[i];
  out[i] = fmaxf(s * h + sB[c], 0.f);
}

// ------------------------------------------------- global max pool over N
__global__ __launch_bounds__(256) void gmax_k(const float* __restrict__ feat,
                                              unsigned* __restrict__ pooled) {
  int b = blockIdx.y, chunk = blockIdx.x;
  int c = threadIdx.x;
  const float* fb = feat + ((size_t)b * Nn + chunk * 32) * 256;
  float m = 0.f;
  #pragma unroll 8
  for (int r = 0; r < 32; ++r) m = fmaxf(m, fb[(size_t)r * 256 + c]);
  atomicMax(&pooled[b * 256 + c], __float_as_uint(m));
}

// ------------------------------------------------- final linear 8x256 @ 256x256
__global__ void final_k(const float* __restrict__ pooled, const float* __restrict__ wo,
                        const float* __restrict__ bo, float* __restrict__ out) {
  int b = blockIdx.x, c = threadIdx.x;
  const float* pr = pooled + b * 256;
  const float* wr = wo + c * 256;
  float s = bo[c];
  for (int j = 0; j < 256; ++j) s += pr[j] * wr[j];
  out[b * 256 + c] = s;
}

// ------------------------------------------------- layer driver
template <int CIN, int COUT>
static void run_layer(const float* fin, const float* W, const float* bias,
                      const float* gamma, const float* beta, float* fout,
                      float* nd, bool big, float* Abuf, float* Bvbuf, int* idxb,
                      float* xx, float* maxh, float* minh, float* gsum,
                      float* sA, float* sB, hipStream_t stream) {
  row_sumsq_k<<<(NPT + 255) / 256, 256, 0, stream>>>(fin, xx, CIN);
  if (big) {
    dist_k<<<dim3(136, 1, Bb), 256, 0, stream>>>(fin, xx, nd, CIN);
    topk_k<<<NPT, 256, 0, stream>>>(nd, idxb);
  } else {
    for (int b = 0; b < Bb; ++b) {
      dist_k<<<dim3(136, 1, 1), 256, 0, stream>>>(
          fin + (size_t)b * Nn * CIN, xx + (size_t)b * Nn, nd, CIN);
      topk_k<<<Nn, 256, 0, stream>>>(nd, idxb + (size_t)b * Nn * KNB);
    }
  }
  gemmAB_k<<<dim3(2 * COUT / 128, NPT / 128), 256, 0, stream>>>(fin, W, bias,
                                                                Abuf, Bvbuf, COUT, CIN);
  hipMemsetAsync(gsum, 0, 2 * 256 * sizeof(float), stream);
  combine_k<COUT><<<NPT / 16, 256, 0, stream>>>(Abuf, Bvbuf, idxb, maxh, minh,
                                                gsum, gsum + 256);
  stats_k<<<1, 256, 0, stream>>>(gsum, gsum + 256, gamma, beta, sA, sB, COUT);
  apply_k<<<(NPT * COUT + 255) / 256, 256, 0, stream>>>(maxh, minh, sA, sB, fout, COUT);
}

extern "C" void kernel_launch(void* const* d_in, const int* in_sizes, int n_in,
                              void* d_out, int out_size, void* d_ws, size_t ws_size,
                              hipStream_t stream) {
  const float* x   = (const float*)d_in[0];
  const float* w1  = (const float*)d_in[1];
  const float* b1  = (const float*)d_in[2];
  const float* g1  = (const float*)d_in[3];
  const float* be1 = (const float*)d_in[4];
  const float* w2  = (const float*)d_in[5];
  const float* b2  = (const float*)d_in[6];
  const float* g2  = (const float*)d_in[7];
  const float* be2 = (const float*)d_in[8];
  const float* w3  = (const float*)d_in[9];
  const float* b3  = (const float*)d_in[10];
  const float* g3  = (const float*)d_in[11];
  const float* be3 = (const float*)d_in[12];
  const float* wo  = (const float*)d_in[13];
  const float* bo  = (const float*)d_in[14];
  float* out = (float*)d_out;

  char* ws = (char*)d_ws;
  size_t off = 0;
  auto grab = [&](size_t bytes) -> char* {
    char* p = ws + off;
    off = (off + bytes + 255) & ~(size_t)255;
    return p;
  };
  const size_t SLAB = (size_t)NPT * 256 * 4;          // 16.78 MB
  const size_t ND_ALL = (size_t)Bb * Nn * Nn * 4;     // 134.2 MB
  const size_t NEED_BIG = ND_ALL + ((size_t)NPT * KNB * 4) + ((size_t)NPT * 4) +
                          ((size_t)NPT * 64 * 4) + ((size_t)NPT * 128 * 4) +
                          (16 << 10) + 16 * 256;
  bool big = (ws_size >= NEED_BIG);

  float *nd, *Abuf, *Bvbuf, *maxh, *minh, *feat3;
  if (big) {
    nd    = (float*)grab(ND_ALL);
    Abuf  = nd;
    Bvbuf = (float*)((char*)nd + SLAB);
    maxh  = (float*)((char*)nd + 2 * SLAB);
    minh  = (float*)((char*)nd + 3 * SLAB);
  } else {
    nd    = (float*)grab((size_t)Nn * Nn * 4);
    Abuf  = nd;
    Bvbuf = (float*)grab(SLAB);
    maxh  = nullptr; minh = nullptr;
  }
  int*   idxb  = (int*)  grab((size_t)NPT * KNB * 4);
  float* xx    = (float*)grab((size_t)NPT * 4);
  float* feat1 = (float*)grab((size_t)NPT * 64 * 4);
  float* feat2 = (float*)grab((size_t)NPT * 128 * 4);
  if (!big) {
    maxh = (float*)grab(SLAB);
    minh = (float*)grab(SLAB);
  }
  feat3 = minh;
  float* gsum  = (float*)grab(2 * 256 * 4);
  float* sA    = (float*)grab(256 * 4);
  float* sB    = (float*)grab(256 * 4);
  unsigned* pooled = (unsigned*)grab(Bb * 256 * 4);

  run_layer<3, 64>(x, w1, b1, g1, be1, feat1, nd, big, Abuf, Bvbuf, idxb, xx,
                   maxh, minh, gsum, sA, sB, stream);
  run_layer<64, 128>(feat1, w2, b2, g2, be2, feat2, nd, big, Abuf, Bvbuf, idxb, xx,
                     maxh, minh, gsum, sA, sB, stream);
  run_layer<128, 256>(feat2, w3, b3, g3, be3, feat3, nd, big, Abuf, Bvbuf, idxb, xx,
                      maxh, minh, gsum, sA, sB, stream);

  hipMemsetAsync(pooled, 0, Bb * 256 * sizeof(unsigned), stream);
  gmax_k<<<dim3(Nn / 32, Bb), 256, 0, stream>>>(feat3, pooled);
  final_k<<<Bb, 256, 0, stream>>>((const float*)pooled, wo, bo, out);
  (void)in_sizes; (void)n_in; (void)out_size;
}

// Round 8
// 911.237 us; speedup vs baseline: 6.1392x; 6.1392x over previous
//
#include <hip/hip_runtime.h>
#include <cmath>

// DGCNN: B=8, N=2048, k=20, dims 3->64->128->256, fp32 throughout.
static constexpr int Bb  = 8;
static constexpr int Nn  = 2048;
static constexpr int KNB = 20;
static constexpr int NPT = Bb * Nn;
#define EPSBN 1e-5f

// LDS column swizzle: maps 4-float groups so 16-address b128 reads cover all
// 32 banks 2x (2-way = free) instead of 4 bank-groups 4x.
__device__ __forceinline__ int permc(int c) { return c ^ (4 * (c >> 5)); }

// ---------------------------------------------------------------- row |x|^2
__global__ __launch_bounds__(256) void row_sumsq_k(const float* __restrict__ f,
                                                   float* __restrict__ xx, int C) {
  int g = blockIdx.x * 256 + threadIdx.x;
  if (g >= NPT) return;
  const float* r = f + (size_t)g * C;
  float s = 0.f;
  for (int j = 0; j < C; ++j) { float v = r[j]; s += v * v; }
  xx[g] = s;
}

// ------------------------------------------------- neg_dist, symmetric 128x128
// nd[n][m] = 2*x_n.x_m - |x_n|^2 - |x_m|^2 ; diag forced to exactly 0.
// Upper-triangular block pairs (136/batch); mirror via 32-row LDS transpose
// chunks (buffer unioned with dead As/Bs -> 16.9 KB).
// HARD-LEARNED (R6/R7): (a) do NOT set launch_bounds min-waves — acc[8][8]
// needs >=64 VGPR; forcing 4 waves/SIMD spilled to scratch (FETCH 37->412 MB).
// (b) do NOT index acc[][] with runtime values — dynamic register indexing
// demotes the array to scratch (R7: VGPR=52, 13 GB scratch traffic, 20x).
__global__ __launch_bounds__(256) void dist_k(const float* __restrict__ f,
                                              const float* __restrict__ xx,
                                              float* __restrict__ nd, int C) {
  __shared__ float lds[32 * 132];                       // 16.9 KB, unioned
  float (*As)[132] = (float(*)[132])lds;                // rows 0..15
  float (*Bs)[132] = (float(*)[132])(lds + 16 * 132);   // rows 16..31
  float* Sc = lds;                                      // transpose buf (32x132)
  int tid = threadIdx.x, tx = tid & 15, ty = tid >> 4;
  int b = blockIdx.z;
  const float* fb  = f  + (size_t)b * Nn * C;
  const float* xxb = xx + (size_t)b * Nn;
  float* ndb = nd + (size_t)b * Nn * Nn;
  // triangular decode: blockIdx.x in [0,136) -> (rblk, cblk), rblk <= cblk
  int p = blockIdx.x, rblk = 0;
  while (p >= 16 - rblk) { p -= 16 - rblk; ++rblk; }
  int rb = rblk * 128, cb = (rblk + p) * 128;
  bool diag = (rb == cb);
  int kk0 = tid & 15, rr = tid >> 4;
  float acc[8][8] = {};
  for (int k0 = 0; k0 < C; k0 += 16) {
    int k = k0 + kk0;
    bool ok = k < C;
    #pragma unroll
    for (int t = 0; t < 8; ++t) {
      int r2 = rr + 16 * t;
      int c2 = permc(r2);
      As[kk0][c2] = ok ? fb[(size_t)(rb + r2) * C + k] : 0.f;
      Bs[kk0][c2] = ok ? fb[(size_t)(cb + r2) * C + k] : 0.f;
    }
    __syncthreads();
    #pragma unroll
    for (int kk = 0; kk < 16; ++kk) {
      float4 a0 = *(const float4*)&As[kk][permc(8 * ty)];
      float4 a1 = *(const float4*)&As[kk][permc(8 * ty + 4)];
      float4 b0 = *(const float4*)&Bs[kk][permc(8 * tx)];
      float4 b1 = *(const float4*)&Bs[kk][permc(8 * tx + 4)];
      float av[8] = {a0.x, a0.y, a0.z, a0.w, a1.x, a1.y, a1.z, a1.w};
      float bv[8] = {b0.x, b0.y, b0.z, b0.w, b1.x, b1.y, b1.z, b1.w};
      #pragma unroll
      for (int i = 0; i < 8; ++i)
        #pragma unroll
        for (int j = 0; j < 8; ++j) acc[i][j] += av[i] * bv[j];
    }
    __syncthreads();
  }
  // epilogue: finalize into acc, store tile (+ mirrored tile if off-diag)
  float xr[8], xc[8];
  #pragma unroll
  for (int i = 0; i < 8; ++i) xr[i] = xxb[rb + 8 * ty + i];
  #pragma unroll
  for (int j = 0; j < 8; ++j) xc[j] = xxb[cb + 8 * tx + j];
  #pragma unroll
  for (int i = 0; i < 8; ++i) {
    int grow = rb + 8 * ty + i;
    #pragma unroll
    for (int j = 0; j < 8; ++j) {
      int gcol = cb + 8 * tx + j;
      float v = 2.f * acc[i][j] - xr[i] - xc[j];
      acc[i][j] = (grow == gcol) ? 0.f : v;
    }
    *(float4*)&ndb[(size_t)grow * Nn + cb + 8 * tx] =
        make_float4(acc[i][0], acc[i][1], acc[i][2], acc[i][3]);
    *(float4*)&ndb[(size_t)grow * Nn + cb + 8 * tx + 4] =
        make_float4(acc[i][4], acc[i][5], acc[i][6], acc[i][7]);
  }
  if (!diag) {
    int lr = tid >> 3, q8 = tid & 7;
    #pragma unroll
    for (int h = 0; h < 4; ++h) {
      __syncthreads();
      if ((tx >> 2) == h) {
        int txl = tx & 3;
        #pragma unroll
        for (int j = 0; j < 8; ++j)
          #pragma unroll
          for (int i = 0; i < 8; ++i)
            Sc[(8 * txl + j) * 132 + 8 * ty + i] = acc[i][j];
      }
      __syncthreads();
      int grow = cb + 32 * h + lr;
      #pragma unroll
      for (int u = 0; u < 4; ++u) {
        float4 v = *(const float4*)&Sc[lr * 132 + 4 * (q8 + 8 * u)];
        *(float4*)&ndb[(size_t)grow * Nn + rb + 4 * (q8 + 8 * u)] = v;
      }
    }
  }
}

// ------------------------------------------------- wave0 suffix-scan digit find
__device__ __forceinline__ void find_digit64(const int* hist, int tid,
                                             int* s_digit, int* s_kneed) {
  if (tid < 64) {
    int kneed = *s_kneed;
    int l = tid;
    int h0 = hist[4 * l], h1 = hist[4 * l + 1], h2 = hist[4 * l + 2], h3 = hist[4 * l + 3];
    int s3 = h3, s2 = h2 + s3, s1 = h1 + s2, s0 = h0 + s1;
    int cum = s0;
    #pragma unroll
    for (int off = 1; off < 64; off <<= 1) {
      int v = __shfl_down(cum, off, 64);
      if (l + off < 64) cum += v;
    }
    int ab = cum - s0;
    int suf0 = ab + s0, suf1 = ab + s1, suf2 = ab + s2, suf3 = ab + s3, suf4 = ab;
    if (suf0 >= kneed && suf1 < kneed) { *s_digit = 4 * l;     *s_kneed = kneed - suf1; }
    if (suf1 >= kneed && suf2 < kneed) { *s_digit = 4 * l + 1; *s_kneed = kneed - suf2; }
    if (suf2 >= kneed && suf3 < kneed) { *s_digit = 4 * l + 2; *s_kneed = kneed - suf3; }
    if (suf3 >= kneed && suf4 < kneed) { *s_digit = 4 * l + 3; *s_kneed = kneed - suf4; }
  }
}

// ------------------------------------------------- top-20: radix select per row
__global__ __launch_bounds__(256) void topk_k(const float* __restrict__ nd,
                                              int* __restrict__ outidx) {
  __shared__ unsigned keys[Nn];
  __shared__ unsigned ck[Nn];
  __shared__ short cidx[Nn];
  __shared__ int hist[256];
  __shared__ int s_digit, s_kneed, s_cnt, s_ncand;
  int tid = threadIdx.x;
  const float* row = nd + (size_t)blockIdx.x * Nn;
  int* orow = outidx + (size_t)blockIdx.x * KNB;
  if (tid == 0) { s_kneed = KNB; s_cnt = 0; s_ncand = 0; }
  hist[tid] = 0;
  __syncthreads();
  #pragma unroll
  for (int t = 0; t < Nn / 256; ++t) {
    int i = tid + 256 * t;
    unsigned u = __float_as_uint(row[i]);
    unsigned k = (u & 0x80000000u) ? ~u : (u | 0x80000000u);
    keys[i] = k;
    atomicAdd(&hist[k >> 24], 1);
  }
  __syncthreads();
  find_digit64(hist, tid, &s_digit, &s_kneed);
  __syncthreads();
  unsigned dig1 = (unsigned)s_digit;
  unsigned prefix = dig1 << 24;
  #pragma unroll
  for (int t = 0; t < Nn / 256; ++t) {
    int i = tid + 256 * t;
    unsigned k = keys[i];
    unsigned bb = k >> 24;
    if (bb > dig1) { int p = atomicAdd(&s_cnt, 1); orow[p] = i; }
    else if (bb == dig1) { int p = atomicAdd(&s_ncand, 1); ck[p] = k; cidx[p] = (short)i; }
  }
  __syncthreads();
  int nc = s_ncand;
  for (int shift = 16; shift >= 0; shift -= 8) {
    unsigned pm = 0xFFFFFFFFu << (shift + 8);
    hist[tid] = 0;
    __syncthreads();
    for (int j = tid; j < nc; j += 256) {
      unsigned k = ck[j];
      if (((k ^ prefix) & pm) == 0) atomicAdd(&hist[(k >> shift) & 255], 1);
    }
    __syncthreads();
    find_digit64(hist, tid, &s_digit, &s_kneed);
    __syncthreads();
    prefix |= ((unsigned)s_digit) << shift;
  }
  unsigned T = prefix;
  for (int j = tid; j < nc; j += 256)
    if (ck[j] > T) { int p = atomicAdd(&s_cnt, 1); orow[p] = (int)cidx[j]; }
  int kF = s_kneed, base = KNB - kF, last = -1;
  for (int r = 0; r < kF; ++r) {
    int loc = 0x7fffffff;
    for (int j = tid; j < nc; j += 256)
      if (ck[j] == T && (int)cidx[j] > last) loc = min(loc, (int)cidx[j]);
    hist[tid] = loc;
    __syncthreads();
    for (int s = 128; s > 0; s >>= 1) {
      if (tid < s) hist[tid] = min(hist[tid], hist[tid + s]);
      __syncthreads();
    }
    last = hist[0];
    if (tid == 0) orow[base + r] = last;
    __syncthreads();
  }
}

// ------------------------------------------------- fused GEMM: A = X*W1^T + b, Bv = X*W2^T
__global__ __launch_bounds__(256) void gemmAB_k(const float* __restrict__ X,
                                                const float* __restrict__ W,
                                                const float* __restrict__ bias,
                                                float* __restrict__ A,
                                                float* __restrict__ Bv,
                                                int COUT, int CIN) {
  __shared__ float Xs[16][132];
  __shared__ float Ws[16][132];
  int tid = threadIdx.x, tx = tid & 15, ty = tid >> 4;
  int mb = blockIdx.y * 128, cb = blockIdx.x * 128;
  int kk0 = tid & 15, rr = tid >> 4;
  int ldw = 2 * CIN;
  float acc[8][8] = {};
  for (int k0 = 0; k0 < CIN; k0 += 16) {
    int k = k0 + kk0;
    bool ok = k < CIN;
    #pragma unroll
    for (int r2 = rr; r2 < 128; r2 += 16) {
      Xs[kk0][permc(r2)] = ok ? X[(size_t)(mb + r2) * CIN + k] : 0.f;
      int c2 = cb + r2;
      const float* wr = (c2 < COUT) ? (W + (size_t)c2 * ldw)
                                    : (W + (size_t)(c2 - COUT) * ldw + CIN);
      Ws[kk0][permc(r2)] = ok ? wr[k] : 0.f;
    }
    __syncthreads();
    #pragma unroll
    for (int kk = 0; kk < 16; ++kk) {
      float4 a0 = *(const float4*)&Xs[kk][permc(8 * ty)];
      float4 a1 = *(const float4*)&Xs[kk][permc(8 * ty + 4)];
      float4 b0 = *(const float4*)&Ws[kk][permc(8 * tx)];
      float4 b1 = *(const float4*)&Ws[kk][permc(8 * tx + 4)];
      float av[8] = {a0.x, a0.y, a0.z, a0.w, a1.x, a1.y, a1.z, a1.w};
      float bv[8] = {b0.x, b0.y, b0.z, b0.w, b1.x, b1.y, b1.z, b1.w};
      #pragma unroll
      for (int i = 0; i < 8; ++i)
        #pragma unroll
        for (int j = 0; j < 8; ++j) acc[i][j] += av[i] * bv[j];
    }
    __syncthreads();
  }
  int c0 = cb + 8 * tx;
  bool isA = (c0 < COUT);
  float bb[8] = {0, 0, 0, 0, 0, 0, 0, 0};
  if (isA) {
    float4 b4a = *(const float4*)&bias[c0];
    float4 b4b = *(const float4*)&bias[c0 + 4];
    bb[0] = b4a.x; bb[1] = b4a.y; bb[2] = b4a.z; bb[3] = b4a.w;
    bb[4] = b4b.x; bb[5] = b4b.y; bb[6] = b4b.z; bb[7] = b4b.w;
  }
  float* dst = isA ? A : Bv;
  int cc = isA ? c0 : (c0 - COUT);
  #pragma unroll
  for (int i = 0; i < 8; ++i) {
    int m = mb + 8 * ty + i;
    *(float4*)&dst[(size_t)m * COUT + cc] =
        make_float4(acc[i][0] + bb[0], acc[i][1] + bb[1], acc[i][2] + bb[2], acc[i][3] + bb[3]);
    *(float4*)&dst[(size_t)m * COUT + cc + 4] =
        make_float4(acc[i][4] + bb[4], acc[i][5] + bb[5], acc[i][6] + bb[6], acc[i][7] + bb[7]);
  }
}

// ------------------------------------------------- gather-combine + stats
// XCD-aware: batch = blockIdx.x % 8 so each XCD's L2 caches one batch's Bv slice.
template <int COUT>
__global__ __launch_bounds__(256) void combine_k(const float* __restrict__ A,
                                                 const float* __restrict__ Bv,
                                                 const int* __restrict__ idx,
                                                 float* __restrict__ maxh,
                                                 float* __restrict__ minh,
                                                 float* __restrict__ gsum,
                                                 float* __restrict__ gsumsq) {
  constexpr int TPP = COUT / 4;
  constexpr int P = 256 / TPP;
  constexpr int PTS = 16;
  __shared__ float red[8][256];
  int tid = threadIdx.x;
  int p = tid / TPP, cq = tid % TPP;
  int b = blockIdx.x & 7, chunk = blockIdx.x >> 3;
  int nbase = b * Nn + chunk * PTS;
  const float4* A4 = (const float4*)A;
  const float4* B4 = (const float4*)Bv;
  float4 ts = make_float4(0, 0, 0, 0), ts2 = make_float4(0, 0, 0, 0);
  for (int it = 0; it < PTS / P; ++it) {
    int n = nbase + it * P + p;
    float4 a  = A4[(size_t)n * TPP + cq];
    float4 bc = B4[(size_t)n * TPP + cq];
    float4 base = make_float4(a.x - bc.x, a.y - bc.y, a.z - bc.z, a.w - bc.w);
    float4 mx = make_float4(-INFINITY, -INFINITY, -INFINITY, -INFINITY);
    float4 mn = make_float4(INFINITY, INFINITY, INFINITY, INFINITY);
    int gb = b * Nn;
    const int* ip = idx + (size_t)n * KNB;
    for (int k = 0; k < KNB; ++k) {
      int m = ip[k];
      float4 bn = B4[(size_t)(gb + m) * TPP + cq];
      float4 h = make_float4(base.x + bn.x, base.y + bn.y, base.z + bn.z, base.w + bn.w);
      mx.x = fmaxf(mx.x, h.x); mx.y = fmaxf(mx.y, h.y);
      mx.z = fmaxf(mx.z, h.z); mx.w = fmaxf(mx.w, h.w);
      mn.x = fminf(mn.x, h.x); mn.y = fminf(mn.y, h.y);
      mn.z = fminf(mn.z, h.z); mn.w = fminf(mn.w, h.w);
      ts.x += h.x; ts.y += h.y; ts.z += h.z; ts.w += h.w;
      ts2.x += h.x * h.x; ts2.y += h.y * h.y; ts2.z += h.z * h.z; ts2.w += h.w * h.w;
    }
    ((float4*)maxh)[(size_t)n * TPP + cq] = mx;
    ((float4*)minh)[(size_t)n * TPP + cq] = mn;
  }
  red[0][tid] = ts.x;  red[1][tid] = ts.y;  red[2][tid] = ts.z;  red[3][tid] = ts.w;
  red[4][tid] = ts2.x; red[5][tid] = ts2.y; red[6][tid] = ts2.z; red[7][tid] = ts2.w;
  __syncthreads();
  if (tid < COUT) {
    int q = tid & 3, g = tid >> 2;
    float s = 0.f, s2 = 0.f;
    for (int pp = 0; pp < P; ++pp) {
      int t2 = pp * TPP + g;
      s += red[q][t2]; s2 += red[4 + q][t2];
    }
    atomicAdd(&gsum[tid], s);
    atomicAdd(&gsumsq[tid], s2);
  }
}

// ------------------------------------------------- BN scale/shift per channel
__global__ void stats_k(const float* __restrict__ gsum, const float* __restrict__ gsumsq,
                        const float* __restrict__ gamma, const float* __restrict__ beta,
                        float* __restrict__ sA, float* __restrict__ sB, int COUT) {
  int c = threadIdx.x;
  if (c < COUT) {
    const float cnt = (float)((size_t)Bb * Nn * KNB);
    float mean = gsum[c] / cnt;
    float var = gsumsq[c] / cnt - mean * mean;
    var = fmaxf(var, 0.f);
    float s = gamma[c] * rsqrtf(var + EPSBN);
    sA[c] = s;
    sB[c] = beta[c] - mean * s;
  }
}

// ------------------------------------------------- apply BN+ReLU
__global__ __launch_bounds__(256) void apply_k(const float* __restrict__ maxh,
                                               const float* __restrict__ minh,
                                               const float* __restrict__ sA,
                                               const float* __restrict__ sB,
                                               float* __restrict__ out, int COUT) {
  int i = blockIdx.x * 256 + threadIdx.x;
  if (i >= NPT * COUT) return;
  int c = i % COUT;
  float s = sA[c];
  float h = (s >= 0.f) ? maxh[i] : minh[i];
  out[i] = fmaxf(s * h + sB[c], 0.f);
}

// ------------------------------------------------- global max pool over N
__global__ __launch_bounds__(256) void gmax_k(const float* __restrict__ feat,
                                              unsigned* __restrict__ pooled) {
  int b = blockIdx.y, chunk = blockIdx.x;
  int c = threadIdx.x;
  const float* fb = feat + ((size_t)b * Nn + chunk * 32) * 256;
  float m = 0.f;
  #pragma unroll 8
  for (int r = 0; r < 32; ++r) m = fmaxf(m, fb[(size_t)r * 256 + c]);
  atomicMax(&pooled[b * 256 + c], __float_as_uint(m));
}

// ------------------------------------------------- final linear 8x256 @ 256x256
__global__ void final_k(const float* __restrict__ pooled, const float* __restrict__ wo,
                        const float* __restrict__ bo, float* __restrict__ out) {
  int b = blockIdx.x, c = threadIdx.x;
  const float* pr = pooled + b * 256;
  const float* wr = wo + c * 256;
  float s = bo[c];
  for (int j = 0; j < 256; ++j) s += pr[j] * wr[j];
  out[b * 256 + c] = s;
}

// ------------------------------------------------- layer driver
template <int CIN, int COUT>
static void run_layer(const float* fin, const float* W, const float* bias,
                      const float* gamma, const float* beta, float* fout,
                      float* nd, bool big, float* Abuf, float* Bvbuf, int* idxb,
                      float* xx, float* maxh, float* minh, float* gsum,
                      float* sA, float* sB, hipStream_t stream) {
  row_sumsq_k<<<(NPT + 255) / 256, 256, 0, stream>>>(fin, xx, CIN);
  if (big) {
    dist_k<<<dim3(136, 1, Bb), 256, 0, stream>>>(fin, xx, nd, CIN);
    topk_k<<<NPT, 256, 0, stream>>>(nd, idxb);
  } else {
    for (int b = 0; b < Bb; ++b) {
      dist_k<<<dim3(136, 1, 1), 256, 0, stream>>>(
          fin + (size_t)b * Nn * CIN, xx + (size_t)b * Nn, nd, CIN);
      topk_k<<<Nn, 256, 0, stream>>>(nd, idxb + (size_t)b * Nn * KNB);
    }
  }
  gemmAB_k<<<dim3(2 * COUT / 128, NPT / 128), 256, 0, stream>>>(fin, W, bias,
                                                                Abuf, Bvbuf, COUT, CIN);
  hipMemsetAsync(gsum, 0, 2 * 256 * sizeof(float), stream);
  combine_k<COUT><<<NPT / 16, 256, 0, stream>>>(Abuf, Bvbuf, idxb, maxh, minh,
                                                gsum, gsum + 256);
  stats_k<<<1, 256, 0, stream>>>(gsum, gsum + 256, gamma, beta, sA, sB, COUT);
  apply_k<<<(NPT * COUT + 255) / 256, 256, 0, stream>>>(maxh, minh, sA, sB, fout, COUT);
}

extern "C" void kernel_launch(void* const* d_in, const int* in_sizes, int n_in,
                              void* d_out, int out_size, void* d_ws, size_t ws_size,
                              hipStream_t stream) {
  const float* x   = (const float*)d_in[0];
  const float* w1  = (const float*)d_in[1];
  const float* b1  = (const float*)d_in[2];
  const float* g1  = (const float*)d_in[3];
  const float* be1 = (const float*)d_in[4];
  const float* w2  = (const float*)d_in[5];
  const float* b2  = (const float*)d_in[6];
  const float* g2  = (const float*)d_in[7];
  const float* be2 = (const float*)d_in[8];
  const float* w3  = (const float*)d_in[9];
  const float* b3  = (const float*)d_in[10];
  const float* g3  = (const float*)d_in[11];
  const float* be3 = (const float*)d_in[12];
  const float* wo  = (const float*)d_in[13];
  const float* bo  = (const float*)d_in[14];
  float* out = (float*)d_out;

  char* ws = (char*)d_ws;
  size_t off = 0;
  auto grab = [&](size_t bytes) -> char* {
    char* p = ws + off;
    off = (off + bytes + 255) & ~(size_t)255;
    return p;
  };
  const size_t SLAB = (size_t)NPT * 256 * 4;          // 16.78 MB
  const size_t ND_ALL = (size_t)Bb * Nn * Nn * 4;     // 134.2 MB
  const size_t NEED_BIG = ND_ALL + ((size_t)NPT * KNB * 4) + ((size_t)NPT * 4) +
                          ((size_t)NPT * 64 * 4) + ((size_t)NPT * 128 * 4) +
                          (16 << 10) + 16 * 256;
  bool big = (ws_size >= NEED_BIG);

  float *nd, *Abuf, *Bvbuf, *maxh, *minh, *feat3;
  if (big) {
    nd    = (float*)grab(ND_ALL);
    Abuf  = nd;
    Bvbuf = (float*)((char*)nd + SLAB);
    maxh  = (float*)((char*)nd + 2 * SLAB);
    minh  = (float*)((char*)nd + 3 * SLAB);
  } else {
    nd    = (float*)grab((size_t)Nn * Nn * 4);
    Abuf  = nd;
    Bvbuf = (float*)grab(SLAB);
    maxh  = nullptr; minh = nullptr;
  }
  int*   idxb  = (int*)  grab((size_t)NPT * KNB * 4);
  float* xx    = (float*)grab((size_t)NPT * 4);
  float* feat1 = (float*)grab((size_t)NPT * 64 * 4);
  float* feat2 = (float*)grab((size_t)NPT * 128 * 4);
  if (!big) {
    maxh = (float*)grab(SLAB);
    minh = (float*)grab(SLAB);
  }
  feat3 = minh;
  float* gsum  = (float*)grab(2 * 256 * 4);
  float* sA    = (float*)grab(256 * 4);
  float* sB    = (float*)grab(256 * 4);
  unsigned* pooled = (unsigned*)grab(Bb * 256 * 4);

  run_layer<3, 64>(x, w1, b1, g1, be1, feat1, nd, big, Abuf, Bvbuf, idxb, xx,
                   maxh, minh, gsum, sA, sB, stream);
  run_layer<64, 128>(feat1, w2, b2, g2, be2, feat2, nd, big, Abuf, Bvbuf, idxb, xx,
                     maxh, minh, gsum, sA, sB, stream);
  run_layer<128, 256>(feat2, w3, b3, g3, be3, feat3, nd, big, Abuf, Bvbuf, idxb, xx,
                      maxh, minh, gsum, sA, sB, stream);

  hipMemsetAsync(pooled, 0, Bb * 256 * sizeof(unsigned), stream);
  gmax_k<<<dim3(Nn / 32, Bb), 256, 0, stream>>>(feat3, pooled);
  final_k<<<Bb, 256, 0, stream>>>((const float*)pooled, wo, bo, out);
  (void)in_sizes; (void)n_in; (void)out_size;
}